// Round 2
// baseline (570.992 us; speedup 1.0000x reference)
//
#include <hip/hip_runtime.h>
#include <stdint.h>

// Problem dims (fixed by reference): B=4, S=2048, K=4096, N=4096
#define M_DIM 8192   // B*S
#define N_DIM 4096
#define K_DIM 4096
#define NKB   (K_DIM / 32)   // 128 scale blocks along K == number of K-steps

typedef __bf16 bf16x8 __attribute__((ext_vector_type(8)));
typedef float  f32x4  __attribute__((ext_vector_type(4)));

// Pack two fp32 -> two bf16 in one dword: round-half-up via +0x8000, then
// v_perm_b32 grabs the high halves. ~3 VALU ops per pair.
// Returns bf16(hi)<<16 | bf16(lo)  (little-endian: lo is element 0).
__device__ __forceinline__ uint32_t pack2_bf16(float lo, float hi) {
    union { float f; uint32_t u; } a, b;
    a.f = lo; b.f = hi;
    return __builtin_amdgcn_perm(b.u + 0x8000u, a.u + 0x8000u, 0x07060302u);
}

// ======================= PATH A: two-pass (uses d_ws) =======================

__global__ void cvt_x_kernel(const float* __restrict__ x,
                             uint32_t* __restrict__ xb, int n8) {
    int i = blockIdx.x * blockDim.x + threadIdx.x;
    if (i >= n8) return;
    const float4* p = (const float4*)x;
    float4 v0 = p[2 * i], v1 = p[2 * i + 1];
    uint4 o;
    o.x = pack2_bf16(v0.x, v0.y);
    o.y = pack2_bf16(v0.z, v0.w);
    o.z = pack2_bf16(v1.x, v1.y);
    o.w = pack2_bf16(v1.z, v1.w);
    ((uint4*)xb)[i] = o;
}

__global__ void dequant_kernel(const int* __restrict__ q,
                               const float* __restrict__ s,
                               uint32_t* __restrict__ wb, int n8) {
    int i = blockIdx.x * blockDim.x + threadIdx.x;
    if (i >= n8) return;
    int base = i << 3;                 // element index in [0, N*K)
    int n = base >> 12;                // / K_DIM
    int k = base & (K_DIM - 1);
    float sc = s[n * NKB + (k >> 5)];  // 8 elems share one 32-block
    float m8 = -8.0f * sc;
    const int4* qp = (const int4*)q;
    int4 q0 = qp[2 * i], q1 = qp[2 * i + 1];
    uint4 o;
    o.x = pack2_bf16(fmaf((float)q0.x, sc, m8), fmaf((float)q0.y, sc, m8));
    o.y = pack2_bf16(fmaf((float)q0.z, sc, m8), fmaf((float)q0.w, sc, m8));
    o.z = pack2_bf16(fmaf((float)q1.x, sc, m8), fmaf((float)q1.y, sc, m8));
    o.w = pack2_bf16(fmaf((float)q1.z, sc, m8), fmaf((float)q1.w, sc, m8));
    ((uint4*)wb)[i] = o;
}

// m97-structure bf16 GEMM: C = A * W^T + bias. A:[M,K] W:[N,K] row-major bf16.
// 128x128 block tile, BK=32, 256 threads = 4 waves of 64x64 (4x4 16x16x32).
__global__ __launch_bounds__(256)
void gemm_bf16_kernel(const __bf16* __restrict__ A,
                      const __bf16* __restrict__ Bw,
                      const float* __restrict__ bias,
                      float* __restrict__ C) {
    __shared__ __align__(16) __bf16 lA[128 * 32];
    __shared__ __align__(16) __bf16 lB[128 * 32];

    const int t    = threadIdx.x;
    const int wave = t >> 6;
    const int lane = t & 63;
    const int bm = blockIdx.y, bn = blockIdx.x;
    const int wm = wave >> 1, wn = wave & 1;

    // 16B chunk idx -> row = idx>>2, k-chunk = (idx&3)*8; LDS dest = idx*16B
    // (lane-contiguous base + lane*16, as global_load_lds requires).
    const int row0 = t >> 2;
    const int c0   = (t & 3) * 8;
    const __bf16* gA0 = A  + (size_t)(bm * 128 + row0) * K_DIM + c0;
    const __bf16* gA1 = A  + (size_t)(bm * 128 + row0 + 64) * K_DIM + c0;
    const __bf16* gB0 = Bw + (size_t)(bn * 128 + row0) * K_DIM + c0;
    const __bf16* gB1 = Bw + (size_t)(bn * 128 + row0 + 64) * K_DIM + c0;
    __bf16* sA0 = lA + t * 8;
    __bf16* sA1 = lA + (256 + t) * 8;
    __bf16* sB0 = lB + t * 8;
    __bf16* sB1 = lB + (256 + t) * 8;

    const int r = lane & 15, quad = lane >> 4;
    const __bf16* fA = lA + (wm * 64 + r) * 32 + quad * 8;
    const __bf16* fB = lB + (wn * 64 + r) * 32 + quad * 8;

    f32x4 acc[4][4] = {};

    for (int kt = 0; kt < NKB; ++kt) {
        __syncthreads();
        __builtin_amdgcn_global_load_lds(
            (const __attribute__((address_space(1))) uint32_t*)gA0,
            (__attribute__((address_space(3))) uint32_t*)sA0, 16, 0, 0);
        __builtin_amdgcn_global_load_lds(
            (const __attribute__((address_space(1))) uint32_t*)gA1,
            (__attribute__((address_space(3))) uint32_t*)sA1, 16, 0, 0);
        __builtin_amdgcn_global_load_lds(
            (const __attribute__((address_space(1))) uint32_t*)gB0,
            (__attribute__((address_space(3))) uint32_t*)sB0, 16, 0, 0);
        __builtin_amdgcn_global_load_lds(
            (const __attribute__((address_space(1))) uint32_t*)gB1,
            (__attribute__((address_space(3))) uint32_t*)sB1, 16, 0, 0);
        gA0 += 32; gA1 += 32; gB0 += 32; gB1 += 32;
        __syncthreads();

        bf16x8 af[4], bfr[4];
#pragma unroll
        for (int i = 0; i < 4; ++i)
            af[i] = *(const bf16x8*)(fA + i * 16 * 32);
#pragma unroll
        for (int j = 0; j < 4; ++j)
            bfr[j] = *(const bf16x8*)(fB + j * 16 * 32);
#pragma unroll
        for (int i = 0; i < 4; ++i)
#pragma unroll
            for (int j = 0; j < 4; ++j)
                acc[i][j] = __builtin_amdgcn_mfma_f32_16x16x32_bf16(
                    af[i], bfr[j], acc[i][j], 0, 0, 0);
    }

    // C/D layout: col = lane&15, row = (lane>>4)*4 + reg  [m89/m91]
    const int m0 = bm * 128 + wm * 64;
    const int n0 = bn * 128 + wn * 64;
#pragma unroll
    for (int j = 0; j < 4; ++j) {
        int col = n0 + j * 16 + r;
        float bv = bias[col];
#pragma unroll
        for (int i = 0; i < 4; ++i) {
            int rbase = m0 + i * 16 + quad * 4;
#pragma unroll
            for (int e = 0; e < 4; ++e)
                C[(size_t)(rbase + e) * N_DIM + col] = acc[i][j][e] + bv;
        }
    }
}

// ================= PATH B: fused, zero workspace ===========================
// Same tile/fragment/epilogue structure; staging converts in registers:
// x fp32 -> bf16, q int32 -> bf16 w = s*(q-8), then ds_write_b128.
__global__ __launch_bounds__(256)
void fused_gemm_kernel(const float* __restrict__ X,
                       const int* __restrict__ Q,
                       const float* __restrict__ S,
                       const float* __restrict__ bias,
                       float* __restrict__ C) {
    __shared__ __align__(16) __bf16 lA[128 * 32];
    __shared__ __align__(16) __bf16 lB[128 * 32];

    const int t    = threadIdx.x;
    const int wave = t >> 6;
    const int lane = t & 63;
    const int bm = blockIdx.y, bn = blockIdx.x;
    const int wm = wave >> 1, wn = wave & 1;

    // Staging: thread t handles tile row srow = t>>1, 16 k-elems at sc0.
    // The 16 elems lie inside ONE 32-wide scale block -> one scale/thread/step.
    const int srow = t >> 1;
    const int sc0  = (t & 1) << 4;
    const float* gX = X + (size_t)(bm * 128 + srow) * K_DIM + sc0;
    const int*   gQ = Q + (size_t)(bn * 128 + srow) * K_DIM + sc0;
    const float* gS = S + (size_t)(bn * 128 + srow) * NKB;
    __bf16* sA = lA + srow * 32 + sc0;
    __bf16* sB = lB + srow * 32 + sc0;

    const int r = lane & 15, quad = lane >> 4;
    const __bf16* fA = lA + (wm * 64 + r) * 32 + quad * 8;
    const __bf16* fB = lB + (wn * 64 + r) * 32 + quad * 8;

    f32x4 acc[4][4] = {};

    // Prologue loads for kt = 0
    float4 x0 = ((const float4*)gX)[0];
    float4 x1 = ((const float4*)gX)[1];
    float4 x2 = ((const float4*)gX)[2];
    float4 x3 = ((const float4*)gX)[3];
    int4 q0 = ((const int4*)gQ)[0];
    int4 q1 = ((const int4*)gQ)[1];
    int4 q2 = ((const int4*)gQ)[2];
    int4 q3 = ((const int4*)gQ)[3];
    float sc = gS[0];

    for (int kt = 0; kt < NKB; ++kt) {
        // Convert in registers (outside the barrier-critical section)
        uint4 pa0, pa1, pb0, pb1;
        pa0.x = pack2_bf16(x0.x, x0.y); pa0.y = pack2_bf16(x0.z, x0.w);
        pa0.z = pack2_bf16(x1.x, x1.y); pa0.w = pack2_bf16(x1.z, x1.w);
        pa1.x = pack2_bf16(x2.x, x2.y); pa1.y = pack2_bf16(x2.z, x2.w);
        pa1.z = pack2_bf16(x3.x, x3.y); pa1.w = pack2_bf16(x3.z, x3.w);
        float m8 = -8.0f * sc;
        pb0.x = pack2_bf16(fmaf((float)q0.x, sc, m8), fmaf((float)q0.y, sc, m8));
        pb0.y = pack2_bf16(fmaf((float)q0.z, sc, m8), fmaf((float)q0.w, sc, m8));
        pb0.z = pack2_bf16(fmaf((float)q1.x, sc, m8), fmaf((float)q1.y, sc, m8));
        pb0.w = pack2_bf16(fmaf((float)q1.z, sc, m8), fmaf((float)q1.w, sc, m8));
        pb1.x = pack2_bf16(fmaf((float)q2.x, sc, m8), fmaf((float)q2.y, sc, m8));
        pb1.y = pack2_bf16(fmaf((float)q2.z, sc, m8), fmaf((float)q2.w, sc, m8));
        pb1.z = pack2_bf16(fmaf((float)q3.x, sc, m8), fmaf((float)q3.y, sc, m8));
        pb1.w = pack2_bf16(fmaf((float)q3.z, sc, m8), fmaf((float)q3.w, sc, m8));

        __syncthreads();   // previous iter's fragment reads complete
        *(uint4*)sA = pa0; *(uint4*)(sA + 8) = pa1;
        *(uint4*)sB = pb0; *(uint4*)(sB + 8) = pb1;
        __syncthreads();   // tile visible to all waves

        if (kt + 1 < NKB) {  // prefetch next step's raw data (overlaps MFMA)
            gX += 32; gQ += 32;
            x0 = ((const float4*)gX)[0];
            x1 = ((const float4*)gX)[1];
            x2 = ((const float4*)gX)[2];
            x3 = ((const float4*)gX)[3];
            q0 = ((const int4*)gQ)[0];
            q1 = ((const int4*)gQ)[1];
            q2 = ((const int4*)gQ)[2];
            q3 = ((const int4*)gQ)[3];
            sc = gS[kt + 1];
        }

        bf16x8 af[4], bfr[4];
#pragma unroll
        for (int i = 0; i < 4; ++i)
            af[i] = *(const bf16x8*)(fA + i * 16 * 32);
#pragma unroll
        for (int j = 0; j < 4; ++j)
            bfr[j] = *(const bf16x8*)(fB + j * 16 * 32);
#pragma unroll
        for (int i = 0; i < 4; ++i)
#pragma unroll
            for (int j = 0; j < 4; ++j)
                acc[i][j] = __builtin_amdgcn_mfma_f32_16x16x32_bf16(
                    af[i], bfr[j], acc[i][j], 0, 0, 0);
    }

    const int m0 = bm * 128 + wm * 64;
    const int n0 = bn * 128 + wn * 64;
#pragma unroll
    for (int j = 0; j < 4; ++j) {
        int col = n0 + j * 16 + r;
        float bv = bias[col];
#pragma unroll
        for (int i = 0; i < 4; ++i) {
            int rbase = m0 + i * 16 + quad * 4;
#pragma unroll
            for (int e = 0; e < 4; ++e)
                C[(size_t)(rbase + e) * N_DIM + col] = acc[i][j][e] + bv;
        }
    }
}

extern "C" void kernel_launch(void* const* d_in, const int* in_sizes, int n_in,
                              void* d_out, int out_size, void* d_ws, size_t ws_size,
                              hipStream_t stream) {
    const float* x    = (const float*)d_in[0];
    const int*   qw   = (const int*)d_in[1];
    const float* sc   = (const float*)d_in[2];
    const float* bias = (const float*)d_in[3];
    float* out = (float*)d_out;

    dim3 grid(N_DIM / 128, M_DIM / 128);

    const size_t need = ((size_t)M_DIM * K_DIM + (size_t)N_DIM * K_DIM) * 2;
    if (ws_size >= need && d_ws != nullptr) {
        // PATH A: two-pass (bf16 conversion cached in workspace)
        uint32_t* xb = (uint32_t*)d_ws;                          // M*K bf16
        uint32_t* wb = xb + (size_t)M_DIM * K_DIM / 2;           // N*K bf16
        int n8x = M_DIM * K_DIM / 8;
        cvt_x_kernel<<<n8x / 256, 256, 0, stream>>>(x, xb, n8x);
        int n8w = N_DIM * K_DIM / 8;
        dequant_kernel<<<n8w / 256, 256, 0, stream>>>(qw, sc, wb, n8w);
        gemm_bf16_kernel<<<grid, 256, 0, stream>>>(
            (const __bf16*)xb, (const __bf16*)wb, bias, out);
    } else {
        // PATH B: fused, zero workspace
        fused_gemm_kernel<<<grid, 256, 0, stream>>>(x, qw, sc, bias, out);
    }
}

// Round 3
// 562.436 us; speedup vs baseline: 1.0152x; 1.0152x over previous
//
#include <hip/hip_runtime.h>
#include <stdint.h>

// Problem dims (fixed by reference): B=4, S=2048, K=4096, N=4096
#define M_DIM 8192   // B*S
#define N_DIM 4096
#define K_DIM 4096
#define NKB   (K_DIM / 32)   // 128 scale blocks along K == number of K-steps

typedef __bf16 bf16x8 __attribute__((ext_vector_type(8)));
typedef float  f32x4  __attribute__((ext_vector_type(4)));

// Pack two fp32 -> two bf16 in one dword: round-half-up via +0x8000, then
// v_perm_b32 grabs the high halves.
__device__ __forceinline__ uint32_t pack2_bf16(float lo, float hi) {
    union { float f; uint32_t u; } a, b;
    a.f = lo; b.f = hi;
    return __builtin_amdgcn_perm(b.u + 0x8000u, a.u + 0x8000u, 0x07060302u);
}

// ======================= PATH A: two-pass (uses d_ws) =======================

__global__ void cvt_x_kernel(const float* __restrict__ x,
                             uint32_t* __restrict__ xb, int n8) {
    int i = blockIdx.x * blockDim.x + threadIdx.x;
    if (i >= n8) return;
    const float4* p = (const float4*)x;
    float4 v0 = p[2 * i], v1 = p[2 * i + 1];
    uint4 o;
    o.x = pack2_bf16(v0.x, v0.y);
    o.y = pack2_bf16(v0.z, v0.w);
    o.z = pack2_bf16(v1.x, v1.y);
    o.w = pack2_bf16(v1.z, v1.w);
    ((uint4*)xb)[i] = o;
}

__global__ void dequant_kernel(const int* __restrict__ q,
                               const float* __restrict__ s,
                               uint32_t* __restrict__ wb, int n8) {
    int i = blockIdx.x * blockDim.x + threadIdx.x;
    if (i >= n8) return;
    int base = i << 3;                 // element index in [0, N*K)
    int n = base >> 12;                // / K_DIM
    int k = base & (K_DIM - 1);
    float sc = s[n * NKB + (k >> 5)];  // 8 elems share one 32-block
    float m8 = -8.0f * sc;
    const int4* qp = (const int4*)q;
    int4 q0 = qp[2 * i], q1 = qp[2 * i + 1];
    uint4 o;
    o.x = pack2_bf16(fmaf((float)q0.x, sc, m8), fmaf((float)q0.y, sc, m8));
    o.y = pack2_bf16(fmaf((float)q0.z, sc, m8), fmaf((float)q0.w, sc, m8));
    o.z = pack2_bf16(fmaf((float)q1.x, sc, m8), fmaf((float)q1.y, sc, m8));
    o.w = pack2_bf16(fmaf((float)q1.z, sc, m8), fmaf((float)q1.w, sc, m8));
    ((uint4*)wb)[i] = o;
}

// m97-structure bf16 GEMM with XOR-swizzled LDS K-chunk placement.
// C = A * W^T + bias. A:[M,K] W:[N,K] row-major bf16. 128x128 tile, BK=32,
// 256 threads = 4 waves of 64x64 (4x4 MFMA tiles of 16x16x32).
//
// Swizzle: LDS slot for tile chunk (row, kc) is kc_lds = kc ^ ((row>>1)&3).
// global_load_lds forces LDS dest = base + lane*16, so the swizzle is applied
// by permuting WHICH global chunk each lane fetches (same 64B row, permuted
// 16B chunks -> identical coalescing). Fragment reads use
// quad_eff = quad ^ ((r>>1)&3); bank position (r&1)*4 + quad_eff spreads
// 16 lanes over 8 x 16B bank groups = 2-way = conflict-free [m136].
__global__ __launch_bounds__(256)
void gemm_bf16_kernel(const __bf16* __restrict__ A,
                      const __bf16* __restrict__ Bw,
                      const float* __restrict__ bias,
                      float* __restrict__ C) {
    __shared__ __align__(16) __bf16 lA[128 * 32];
    __shared__ __align__(16) __bf16 lB[128 * 32];

    const int t    = threadIdx.x;
    const int wave = t >> 6;
    const int lane = t & 63;
    const int bm = blockIdx.y, bn = blockIdx.x;
    const int wm = wave >> 1, wn = wave & 1;

    // Staging: thread t fills LDS chunks t and 256+t (16B each).
    // LDS chunk idx -> row = idx>>2, kc_lds = idx&3; the GLOBAL chunk fetched
    // is kc_g = kc_lds ^ ((row>>1)&3). Rows of the two chunks differ by 64,
    // which doesn't change (row>>1)&3, so kc_g is shared.
    const int row0 = t >> 2;
    const int kc_g = (t & 3) ^ ((row0 >> 1) & 3);
    const int c0   = kc_g * 8;
    const __bf16* gA0 = A  + (size_t)(bm * 128 + row0) * K_DIM + c0;
    const __bf16* gA1 = A  + (size_t)(bm * 128 + row0 + 64) * K_DIM + c0;
    const __bf16* gB0 = Bw + (size_t)(bn * 128 + row0) * K_DIM + c0;
    const __bf16* gB1 = Bw + (size_t)(bn * 128 + row0 + 64) * K_DIM + c0;
    __bf16* sA0 = lA + t * 8;
    __bf16* sA1 = lA + (256 + t) * 8;
    __bf16* sB0 = lB + t * 8;
    __bf16* sB1 = lB + (256 + t) * 8;

    // Fragment reads: lane holds A[row = base + r][k = quad*8 .. +7]; the
    // chunk lives at swizzled slot quad ^ ((r>>1)&3). wm*64 and i*16 don't
    // touch row bits 1-2, so the swizzle term is loop-invariant.
    const int r = lane & 15, quad = lane >> 4;
    const int qsw = quad ^ ((r >> 1) & 3);
    const __bf16* fA = lA + (wm * 64 + r) * 32 + qsw * 8;
    const __bf16* fB = lB + (wn * 64 + r) * 32 + qsw * 8;

    f32x4 acc[4][4] = {};

    for (int kt = 0; kt < NKB; ++kt) {
        __syncthreads();
        __builtin_amdgcn_global_load_lds(
            (const __attribute__((address_space(1))) uint32_t*)gA0,
            (__attribute__((address_space(3))) uint32_t*)sA0, 16, 0, 0);
        __builtin_amdgcn_global_load_lds(
            (const __attribute__((address_space(1))) uint32_t*)gA1,
            (__attribute__((address_space(3))) uint32_t*)sA1, 16, 0, 0);
        __builtin_amdgcn_global_load_lds(
            (const __attribute__((address_space(1))) uint32_t*)gB0,
            (__attribute__((address_space(3))) uint32_t*)sB0, 16, 0, 0);
        __builtin_amdgcn_global_load_lds(
            (const __attribute__((address_space(1))) uint32_t*)gB1,
            (__attribute__((address_space(3))) uint32_t*)sB1, 16, 0, 0);
        gA0 += 32; gA1 += 32; gB0 += 32; gB1 += 32;
        __syncthreads();

        bf16x8 af[4], bfr[4];
#pragma unroll
        for (int i = 0; i < 4; ++i)
            af[i] = *(const bf16x8*)(fA + i * 16 * 32);
#pragma unroll
        for (int j = 0; j < 4; ++j)
            bfr[j] = *(const bf16x8*)(fB + j * 16 * 32);
#pragma unroll
        for (int i = 0; i < 4; ++i)
#pragma unroll
            for (int j = 0; j < 4; ++j)
                acc[i][j] = __builtin_amdgcn_mfma_f32_16x16x32_bf16(
                    af[i], bfr[j], acc[i][j], 0, 0, 0);
    }

    // C/D layout: col = lane&15, row = (lane>>4)*4 + reg  [m89/m91]
    const int m0 = bm * 128 + wm * 64;
    const int n0 = bn * 128 + wn * 64;
#pragma unroll
    for (int j = 0; j < 4; ++j) {
        int col = n0 + j * 16 + r;
        float bv = bias[col];
#pragma unroll
        for (int i = 0; i < 4; ++i) {
            int rbase = m0 + i * 16 + quad * 4;
#pragma unroll
            for (int e = 0; e < 4; ++e)
                C[(size_t)(rbase + e) * N_DIM + col] = acc[i][j][e] + bv;
        }
    }
}

// ================= PATH B: fused, zero workspace (fallback) ================
__global__ __launch_bounds__(256)
void fused_gemm_kernel(const float* __restrict__ X,
                       const int* __restrict__ Q,
                       const float* __restrict__ S,
                       const float* __restrict__ bias,
                       float* __restrict__ C) {
    __shared__ __align__(16) __bf16 lA[128 * 32];
    __shared__ __align__(16) __bf16 lB[128 * 32];

    const int t    = threadIdx.x;
    const int wave = t >> 6;
    const int lane = t & 63;
    const int bm = blockIdx.y, bn = blockIdx.x;
    const int wm = wave >> 1, wn = wave & 1;

    const int srow = t >> 1;
    const int sc0  = (t & 1) << 4;
    const float* gX = X + (size_t)(bm * 128 + srow) * K_DIM + sc0;
    const int*   gQ = Q + (size_t)(bn * 128 + srow) * K_DIM + sc0;
    const float* gS = S + (size_t)(bn * 128 + srow) * NKB;
    __bf16* sA = lA + srow * 32 + sc0;
    __bf16* sB = lB + srow * 32 + sc0;

    const int r = lane & 15, quad = lane >> 4;
    const __bf16* fA = lA + (wm * 64 + r) * 32 + quad * 8;
    const __bf16* fB = lB + (wn * 64 + r) * 32 + quad * 8;

    f32x4 acc[4][4] = {};

    float4 x0 = ((const float4*)gX)[0];
    float4 x1 = ((const float4*)gX)[1];
    float4 x2 = ((const float4*)gX)[2];
    float4 x3 = ((const float4*)gX)[3];
    int4 q0 = ((const int4*)gQ)[0];
    int4 q1 = ((const int4*)gQ)[1];
    int4 q2 = ((const int4*)gQ)[2];
    int4 q3 = ((const int4*)gQ)[3];
    float sc = gS[0];

    for (int kt = 0; kt < NKB; ++kt) {
        uint4 pa0, pa1, pb0, pb1;
        pa0.x = pack2_bf16(x0.x, x0.y); pa0.y = pack2_bf16(x0.z, x0.w);
        pa0.z = pack2_bf16(x1.x, x1.y); pa0.w = pack2_bf16(x1.z, x1.w);
        pa1.x = pack2_bf16(x2.x, x2.y); pa1.y = pack2_bf16(x2.z, x2.w);
        pa1.z = pack2_bf16(x3.x, x3.y); pa1.w = pack2_bf16(x3.z, x3.w);
        float m8 = -8.0f * sc;
        pb0.x = pack2_bf16(fmaf((float)q0.x, sc, m8), fmaf((float)q0.y, sc, m8));
        pb0.y = pack2_bf16(fmaf((float)q0.z, sc, m8), fmaf((float)q0.w, sc, m8));
        pb0.z = pack2_bf16(fmaf((float)q1.x, sc, m8), fmaf((float)q1.y, sc, m8));
        pb0.w = pack2_bf16(fmaf((float)q1.z, sc, m8), fmaf((float)q1.w, sc, m8));
        pb1.x = pack2_bf16(fmaf((float)q2.x, sc, m8), fmaf((float)q2.y, sc, m8));
        pb1.y = pack2_bf16(fmaf((float)q2.z, sc, m8), fmaf((float)q2.w, sc, m8));
        pb1.z = pack2_bf16(fmaf((float)q3.x, sc, m8), fmaf((float)q3.y, sc, m8));
        pb1.w = pack2_bf16(fmaf((float)q3.z, sc, m8), fmaf((float)q3.w, sc, m8));

        __syncthreads();
        *(uint4*)sA = pa0; *(uint4*)(sA + 8) = pa1;
        *(uint4*)sB = pb0; *(uint4*)(sB + 8) = pb1;
        __syncthreads();

        if (kt + 1 < NKB) {
            gX += 32; gQ += 32;
            x0 = ((const float4*)gX)[0];
            x1 = ((const float4*)gX)[1];
            x2 = ((const float4*)gX)[2];
            x3 = ((const float4*)gX)[3];
            q0 = ((const int4*)gQ)[0];
            q1 = ((const int4*)gQ)[1];
            q2 = ((const int4*)gQ)[2];
            q3 = ((const int4*)gQ)[3];
            sc = gS[kt + 1];
        }

        bf16x8 af[4], bfr[4];
#pragma unroll
        for (int i = 0; i < 4; ++i)
            af[i] = *(const bf16x8*)(fA + i * 16 * 32);
#pragma unroll
        for (int j = 0; j < 4; ++j)
            bfr[j] = *(const bf16x8*)(fB + j * 16 * 32);
#pragma unroll
        for (int i = 0; i < 4; ++i)
#pragma unroll
            for (int j = 0; j < 4; ++j)
                acc[i][j] = __builtin_amdgcn_mfma_f32_16x16x32_bf16(
                    af[i], bfr[j], acc[i][j], 0, 0, 0);
    }

    const int m0 = bm * 128 + wm * 64;
    const int n0 = bn * 128 + wn * 64;
#pragma unroll
    for (int j = 0; j < 4; ++j) {
        int col = n0 + j * 16 + r;
        float bv = bias[col];
#pragma unroll
        for (int i = 0; i < 4; ++i) {
            int rbase = m0 + i * 16 + quad * 4;
#pragma unroll
            for (int e = 0; e < 4; ++e)
                C[(size_t)(rbase + e) * N_DIM + col] = acc[i][j][e] + bv;
        }
    }
}

extern "C" void kernel_launch(void* const* d_in, const int* in_sizes, int n_in,
                              void* d_out, int out_size, void* d_ws, size_t ws_size,
                              hipStream_t stream) {
    const float* x    = (const float*)d_in[0];
    const int*   qw   = (const int*)d_in[1];
    const float* sc   = (const float*)d_in[2];
    const float* bias = (const float*)d_in[3];
    float* out = (float*)d_out;

    dim3 grid(N_DIM / 128, M_DIM / 128);

    const size_t need = ((size_t)M_DIM * K_DIM + (size_t)N_DIM * K_DIM) * 2;
    if (ws_size >= need && d_ws != nullptr) {
        uint32_t* xb = (uint32_t*)d_ws;                          // M*K bf16
        uint32_t* wb = xb + (size_t)M_DIM * K_DIM / 2;           // N*K bf16
        int n8x = M_DIM * K_DIM / 8;
        cvt_x_kernel<<<n8x / 256, 256, 0, stream>>>(x, xb, n8x);
        int n8w = N_DIM * K_DIM / 8;
        dequant_kernel<<<n8w / 256, 256, 0, stream>>>(qw, sc, wb, n8w);
        gemm_bf16_kernel<<<grid, 256, 0, stream>>>(
            (const __bf16*)xb, (const __bf16*)wb, bias, out);
    } else {
        fused_gemm_kernel<<<grid, 256, 0, stream>>>(x, qw, sc, bias, out);
    }
}

// Round 4
// 537.118 us; speedup vs baseline: 1.0631x; 1.0471x over previous
//
#include <hip/hip_runtime.h>
#include <stdint.h>

// Problem dims (fixed by reference): B=4, S=2048, K=4096, N=4096
#define M_DIM 8192   // B*S
#define N_DIM 4096
#define K_DIM 4096
#define NKB   (K_DIM / 32)   // scale blocks along K
#define BK    64             // GEMM K-tile
#define KSTEPS (K_DIM / BK)  // 64

typedef __bf16 bf16x8 __attribute__((ext_vector_type(8)));
typedef float  f32x4  __attribute__((ext_vector_type(4)));

// Pack two fp32 -> two bf16 in one dword: round-half-up via +0x8000, then
// v_perm_b32 grabs the high halves.
__device__ __forceinline__ uint32_t pack2_bf16(float lo, float hi) {
    union { float f; uint32_t u; } a, b;
    a.f = lo; b.f = hi;
    return __builtin_amdgcn_perm(b.u + 0x8000u, a.u + 0x8000u, 0x07060302u);
}

// ======================= PATH A: two-pass (uses d_ws) =======================

__global__ void cvt_x_kernel(const float* __restrict__ x,
                             uint32_t* __restrict__ xb, int n8) {
    int i = blockIdx.x * blockDim.x + threadIdx.x;
    if (i >= n8) return;
    const float4* p = (const float4*)x;
    float4 v0 = p[2 * i], v1 = p[2 * i + 1];
    uint4 o;
    o.x = pack2_bf16(v0.x, v0.y);
    o.y = pack2_bf16(v0.z, v0.w);
    o.z = pack2_bf16(v1.x, v1.y);
    o.w = pack2_bf16(v1.z, v1.w);
    ((uint4*)xb)[i] = o;
}

__global__ void dequant_kernel(const int* __restrict__ q,
                               const float* __restrict__ s,
                               uint32_t* __restrict__ wb, int n8) {
    int i = blockIdx.x * blockDim.x + threadIdx.x;
    if (i >= n8) return;
    int base = i << 3;                 // element index in [0, N*K)
    int n = base >> 12;                // / K_DIM
    int k = base & (K_DIM - 1);
    float sc = s[n * NKB + (k >> 5)];  // 8 elems share one 32-block
    float m8 = -8.0f * sc;
    const int4* qp = (const int4*)q;
    int4 q0 = qp[2 * i], q1 = qp[2 * i + 1];
    uint4 o;
    o.x = pack2_bf16(fmaf((float)q0.x, sc, m8), fmaf((float)q0.y, sc, m8));
    o.y = pack2_bf16(fmaf((float)q0.z, sc, m8), fmaf((float)q0.w, sc, m8));
    o.z = pack2_bf16(fmaf((float)q1.x, sc, m8), fmaf((float)q1.y, sc, m8));
    o.w = pack2_bf16(fmaf((float)q1.z, sc, m8), fmaf((float)q1.w, sc, m8));
    ((uint4*)wb)[i] = o;
}

// Restructured-K-loop bf16 GEMM: C = A * W^T + bias.
// 128x128 tile, BK=64, 256 threads = 4 waves of 64x64 (4x4x2 MFMA 16x16x32).
//
// Key change vs m97 structure: global_load_lds for tile kt+1 is issued AFTER
// the "all waves finished reading LDS" barrier and BEFORE the MFMA block, so
// the compiler's mandatory `s_waitcnt vmcnt(0)` lands at the NEXT iteration's
// first barrier — with the whole MFMA phase in flight to hide load latency.
//
// Swizzle: LDS slot for 16B chunk (row, c) is c ^ (row&7) (8 chunks/row at
// BK=64). Fragment reads hit 8 bank groups x 2 lanes = 2-way = free [m136].
__global__ __launch_bounds__(256)
void gemm_bf16_kernel(const __bf16* __restrict__ A,
                      const __bf16* __restrict__ Bw,
                      const float* __restrict__ bias,
                      float* __restrict__ C) {
    __shared__ __align__(16) __bf16 lA[128 * BK];   // 16 KB
    __shared__ __align__(16) __bf16 lB[128 * BK];   // 16 KB

    const int t    = threadIdx.x;
    const int wave = t >> 6;
    const int lane = t & 63;
    const int bm = blockIdx.y, bn = blockIdx.x;
    const int wm = wave >> 1, wn = wave & 1;

    // Staging: thread t fills LDS chunks t, t+256, t+512, t+768 (16B each).
    // chunk idx -> row = idx>>3, c_lds = idx&7. Fetched global chunk
    // c_g = c_lds ^ (row&7); (idx+256)>>3 adds 32 to row, (row&7) unchanged,
    // so c_g is identical for all 4 chunks of a thread.
    const int trow = t >> 3;                    // 0..31
    const int cg   = (t & 7) ^ (trow & 7);
    const __bf16* gA = A  + (size_t)(bm * 128 + trow) * K_DIM + cg * 8;
    const __bf16* gB = Bw + (size_t)(bn * 128 + trow) * K_DIM + cg * 8;

#define ISSUE_LOADS()                                                         \
    do {                                                                      \
        _Pragma("unroll")                                                     \
        for (int kk = 0; kk < 4; ++kk) {                                      \
            __builtin_amdgcn_global_load_lds(                                 \
                (const __attribute__((address_space(1))) uint32_t*)           \
                    (gA + (size_t)(32 * kk) * K_DIM),                         \
                (__attribute__((address_space(3))) uint32_t*)                 \
                    (lA + (t + 256 * kk) * 8), 16, 0, 0);                     \
            __builtin_amdgcn_global_load_lds(                                 \
                (const __attribute__((address_space(1))) uint32_t*)           \
                    (gB + (size_t)(32 * kk) * K_DIM),                         \
                (__attribute__((address_space(3))) uint32_t*)                 \
                    (lB + (t + 256 * kk) * 8), 16, 0, 0);                     \
        }                                                                     \
    } while (0)

    // Fragment reads: lane wants row R = base + r, k = h*32 + quad*8 + j.
    // Chunk c = h*4 + quad lives at slot c ^ (R&7); R&7 = r&7 (base, i*16
    // are multiples of 8... wm*64/i*16 are multiples of 16 >= 8).
    const int r = lane & 15, quad = lane >> 4;
    const int s0 = quad ^ (r & 7);             // slot for h=0; h=1 is s0^4
    const __bf16* fA = lA + (wm * 64 + r) * BK;
    const __bf16* fB = lB + (wn * 64 + r) * BK;

    f32x4 acc[4][4] = {};

    ISSUE_LOADS();   // tile 0 in flight

    for (int kt = 0; kt < KSTEPS; ++kt) {
        __syncthreads();   // drains vmcnt(0): tile kt resident (overlapped
                           // by previous iteration's MFMA phase)
        bf16x8 af[2][4], bfr[2][4];
#pragma unroll
        for (int i = 0; i < 4; ++i) {
            af[0][i]  = *(const bf16x8*)(fA + i * 16 * BK + s0 * 8);
            af[1][i]  = *(const bf16x8*)(fA + i * 16 * BK + (s0 ^ 4) * 8);
            bfr[0][i] = *(const bf16x8*)(fB + i * 16 * BK + s0 * 8);
            bfr[1][i] = *(const bf16x8*)(fB + i * 16 * BK + (s0 ^ 4) * 8);
        }
        __syncthreads();   // all waves done reading LDS; safe to overwrite

        if (kt + 1 < KSTEPS) {
            gA += BK; gB += BK;
            ISSUE_LOADS();   // issued BEFORE MFMA: stays in flight across it
        }

#pragma unroll
        for (int h = 0; h < 2; ++h)
#pragma unroll
            for (int i = 0; i < 4; ++i)
#pragma unroll
                for (int j = 0; j < 4; ++j)
                    acc[i][j] = __builtin_amdgcn_mfma_f32_16x16x32_bf16(
                        af[h][i], bfr[h][j], acc[i][j], 0, 0, 0);
    }
#undef ISSUE_LOADS

    // C/D layout: col = lane&15, row = (lane>>4)*4 + reg  [m89/m91]
    const int m0 = bm * 128 + wm * 64;
    const int n0 = bn * 128 + wn * 64;
#pragma unroll
    for (int j = 0; j < 4; ++j) {
        int col = n0 + j * 16 + r;
        float bv = bias[col];
#pragma unroll
        for (int i = 0; i < 4; ++i) {
            int rbase = m0 + i * 16 + quad * 4;
#pragma unroll
            for (int e = 0; e < 4; ++e)
                C[(size_t)(rbase + e) * N_DIM + col] = acc[i][j][e] + bv;
        }
    }
}

// ================= PATH B: fused, zero workspace (fallback) ================
__global__ __launch_bounds__(256)
void fused_gemm_kernel(const float* __restrict__ X,
                       const int* __restrict__ Q,
                       const float* __restrict__ S,
                       const float* __restrict__ bias,
                       float* __restrict__ C) {
    __shared__ __align__(16) __bf16 lA[128 * 32];
    __shared__ __align__(16) __bf16 lB[128 * 32];

    const int t    = threadIdx.x;
    const int wave = t >> 6;
    const int lane = t & 63;
    const int bm = blockIdx.y, bn = blockIdx.x;
    const int wm = wave >> 1, wn = wave & 1;

    const int srow = t >> 1;
    const int sc0  = (t & 1) << 4;
    const float* gX = X + (size_t)(bm * 128 + srow) * K_DIM + sc0;
    const int*   gQ = Q + (size_t)(bn * 128 + srow) * K_DIM + sc0;
    const float* gS = S + (size_t)(bn * 128 + srow) * NKB;
    __bf16* sA = lA + srow * 32 + sc0;
    __bf16* sB = lB + srow * 32 + sc0;

    const int r = lane & 15, quad = lane >> 4;
    const __bf16* fA = lA + (wm * 64 + r) * 32 + quad * 8;
    const __bf16* fB = lB + (wn * 64 + r) * 32 + quad * 8;

    f32x4 acc[4][4] = {};

    float4 x0 = ((const float4*)gX)[0];
    float4 x1 = ((const float4*)gX)[1];
    float4 x2 = ((const float4*)gX)[2];
    float4 x3 = ((const float4*)gX)[3];
    int4 q0 = ((const int4*)gQ)[0];
    int4 q1 = ((const int4*)gQ)[1];
    int4 q2 = ((const int4*)gQ)[2];
    int4 q3 = ((const int4*)gQ)[3];
    float sc = gS[0];

    for (int kt = 0; kt < NKB; ++kt) {
        uint4 pa0, pa1, pb0, pb1;
        pa0.x = pack2_bf16(x0.x, x0.y); pa0.y = pack2_bf16(x0.z, x0.w);
        pa0.z = pack2_bf16(x1.x, x1.y); pa0.w = pack2_bf16(x1.z, x1.w);
        pa1.x = pack2_bf16(x2.x, x2.y); pa1.y = pack2_bf16(x2.z, x2.w);
        pa1.z = pack2_bf16(x3.x, x3.y); pa1.w = pack2_bf16(x3.z, x3.w);
        float m8 = -8.0f * sc;
        pb0.x = pack2_bf16(fmaf((float)q0.x, sc, m8), fmaf((float)q0.y, sc, m8));
        pb0.y = pack2_bf16(fmaf((float)q0.z, sc, m8), fmaf((float)q0.w, sc, m8));
        pb0.z = pack2_bf16(fmaf((float)q1.x, sc, m8), fmaf((float)q1.y, sc, m8));
        pb0.w = pack2_bf16(fmaf((float)q1.z, sc, m8), fmaf((float)q1.w, sc, m8));
        pb1.x = pack2_bf16(fmaf((float)q2.x, sc, m8), fmaf((float)q2.y, sc, m8));
        pb1.y = pack2_bf16(fmaf((float)q2.z, sc, m8), fmaf((float)q2.w, sc, m8));
        pb1.z = pack2_bf16(fmaf((float)q3.x, sc, m8), fmaf((float)q3.y, sc, m8));
        pb1.w = pack2_bf16(fmaf((float)q3.z, sc, m8), fmaf((float)q3.w, sc, m8));

        __syncthreads();
        *(uint4*)sA = pa0; *(uint4*)(sA + 8) = pa1;
        *(uint4*)sB = pb0; *(uint4*)(sB + 8) = pb1;
        __syncthreads();

        if (kt + 1 < NKB) {
            gX += 32; gQ += 32;
            x0 = ((const float4*)gX)[0];
            x1 = ((const float4*)gX)[1];
            x2 = ((const float4*)gX)[2];
            x3 = ((const float4*)gX)[3];
            q0 = ((const int4*)gQ)[0];
            q1 = ((const int4*)gQ)[1];
            q2 = ((const int4*)gQ)[2];
            q3 = ((const int4*)gQ)[3];
            sc = gS[kt + 1];
        }

        bf16x8 af[4], bfr[4];
#pragma unroll
        for (int i = 0; i < 4; ++i)
            af[i] = *(const bf16x8*)(fA + i * 16 * 32);
#pragma unroll
        for (int j = 0; j < 4; ++j)
            bfr[j] = *(const bf16x8*)(fB + j * 16 * 32);
#pragma unroll
        for (int i = 0; i < 4; ++i)
#pragma unroll
            for (int j = 0; j < 4; ++j)
                acc[i][j] = __builtin_amdgcn_mfma_f32_16x16x32_bf16(
                    af[i], bfr[j], acc[i][j], 0, 0, 0);
    }

    const int m0 = bm * 128 + wm * 64;
    const int n0 = bn * 128 + wn * 64;
#pragma unroll
    for (int j = 0; j < 4; ++j) {
        int col = n0 + j * 16 + r;
        float bv = bias[col];
#pragma unroll
        for (int i = 0; i < 4; ++i) {
            int rbase = m0 + i * 16 + quad * 4;
#pragma unroll
            for (int e = 0; e < 4; ++e)
                C[(size_t)(rbase + e) * N_DIM + col] = acc[i][j][e] + bv;
        }
    }
}

extern "C" void kernel_launch(void* const* d_in, const int* in_sizes, int n_in,
                              void* d_out, int out_size, void* d_ws, size_t ws_size,
                              hipStream_t stream) {
    const float* x    = (const float*)d_in[0];
    const int*   qw   = (const int*)d_in[1];
    const float* sc   = (const float*)d_in[2];
    const float* bias = (const float*)d_in[3];
    float* out = (float*)d_out;

    dim3 grid(N_DIM / 128, M_DIM / 128);

    const size_t need = ((size_t)M_DIM * K_DIM + (size_t)N_DIM * K_DIM) * 2;
    if (ws_size >= need && d_ws != nullptr) {
        uint32_t* xb = (uint32_t*)d_ws;                          // M*K bf16
        uint32_t* wb = xb + (size_t)M_DIM * K_DIM / 2;           // N*K bf16
        int n8x = M_DIM * K_DIM / 8;
        cvt_x_kernel<<<n8x / 256, 256, 0, stream>>>(x, xb, n8x);
        int n8w = N_DIM * K_DIM / 8;
        dequant_kernel<<<n8w / 256, 256, 0, stream>>>(qw, sc, wb, n8w);
        gemm_bf16_kernel<<<grid, 256, 0, stream>>>(
            (const __bf16*)xb, (const __bf16*)wb, bias, out);
    } else {
        fused_gemm_kernel<<<grid, 256, 0, stream>>>(x, qw, sc, bias, out);
    }
}